// Round 9
// baseline (586.932 us; speedup 1.0000x reference)
//
#include <hip/hip_runtime.h>
#include <cstdint>
#include <cstddef>

// Problem constants
#define T_TOK 8192    // B*S tokens
#define DM    2048    // d_model
#define DI    4096    // d_inner
#define TWO_DI 8192

typedef __attribute__((ext_vector_type(8))) short bf16x8;
typedef __attribute__((ext_vector_type(4))) float f32x4;

__device__ __forceinline__ unsigned short f2bf(float f) {
  union { float f; unsigned u; } c; c.f = f;
  unsigned u = c.u;
  unsigned r = (u + 0x7fffu + ((u >> 16) & 1u)) >> 16;  // RNE
  return (unsigned short)r;
}

// ---------------------------------------------------------------------------
// LayerNorm over last dim (2048) + cast to bf16. One block per token.
// ---------------------------------------------------------------------------
__global__ __launch_bounds__(256) void ln_kernel(
    const float* __restrict__ x, const float* __restrict__ gamma,
    const float* __restrict__ beta, unsigned short* __restrict__ xn) {
  const int t = blockIdx.x;
  const int tid = threadIdx.x;
  const float* row = x + (size_t)t * DM;
  float4 v0 = reinterpret_cast<const float4*>(row)[tid];
  float4 v1 = reinterpret_cast<const float4*>(row)[tid + 256];
  float s  = v0.x + v0.y + v0.z + v0.w + v1.x + v1.y + v1.z + v1.w;
  float ss = v0.x*v0.x + v0.y*v0.y + v0.z*v0.z + v0.w*v0.w
           + v1.x*v1.x + v1.y*v1.y + v1.z*v1.z + v1.w*v1.w;
  #pragma unroll
  for (int off = 32; off > 0; off >>= 1) {
    s  += __shfl_down(s, off);
    ss += __shfl_down(ss, off);
  }
  __shared__ float red[8];
  __shared__ float mu_s, inv_s;
  if ((tid & 63) == 0) { red[tid >> 6] = s; red[4 + (tid >> 6)] = ss; }
  __syncthreads();
  if (tid == 0) {
    float S  = red[0] + red[1] + red[2] + red[3];
    float SS = red[4] + red[5] + red[6] + red[7];
    float mu  = S * (1.0f / DM);
    float var = SS * (1.0f / DM) - mu * mu;
    mu_s = mu;
    inv_s = rsqrtf(var + 1e-5f);
  }
  __syncthreads();
  const float mu = mu_s, inv = inv_s;
  float4 g0 = reinterpret_cast<const float4*>(gamma)[tid];
  float4 b0 = reinterpret_cast<const float4*>(beta)[tid];
  float4 g1 = reinterpret_cast<const float4*>(gamma)[tid + 256];
  float4 b1 = reinterpret_cast<const float4*>(beta)[tid + 256];
  ushort4 o0, o1;
  o0.x = f2bf((v0.x - mu) * inv * g0.x + b0.x);
  o0.y = f2bf((v0.y - mu) * inv * g0.y + b0.y);
  o0.z = f2bf((v0.z - mu) * inv * g0.z + b0.z);
  o0.w = f2bf((v0.w - mu) * inv * g0.w + b0.w);
  o1.x = f2bf((v1.x - mu) * inv * g1.x + b1.x);
  o1.y = f2bf((v1.y - mu) * inv * g1.y + b1.y);
  o1.z = f2bf((v1.z - mu) * inv * g1.z + b1.z);
  o1.w = f2bf((v1.w - mu) * inv * g1.w + b1.w);
  reinterpret_cast<ushort4*>(xn + (size_t)t * DM)[tid]       = o0;
  reinterpret_cast<ushort4*>(xn + (size_t)t * DM)[tid + 256] = o1;
}

// ---------------------------------------------------------------------------
// fp32 -> bf16 conversion for BOTH weight matrices in one launch.
// ---------------------------------------------------------------------------
__global__ __launch_bounds__(256) void cvt_both(
    const float* __restrict__ a, unsigned short* __restrict__ oa, int n4a,
    const float* __restrict__ b, unsigned short* __restrict__ ob, int n4b) {
  int i = blockIdx.x * 256 + threadIdx.x;
  const float* src;
  unsigned short* dst;
  int idx;
  if (i < n4a) { src = a; dst = oa; idx = i; }
  else { idx = i - n4a; if (idx >= n4b) return; src = b; dst = ob; }
  float4 v = reinterpret_cast<const float4*>(src)[idx];
  ushort4 o;
  o.x = f2bf(v.x); o.y = f2bf(v.y); o.z = f2bf(v.z); o.w = f2bf(v.w);
  reinterpret_cast<ushort4*>(dst)[idx] = o;
}

// ---------------------------------------------------------------------------
// softmax(-dt) over 4096 elems. Single block.
// ---------------------------------------------------------------------------
__global__ __launch_bounds__(256) void dt_softmax(
    const float* __restrict__ dt, float* __restrict__ w) {
  const int tid = threadIdx.x;
  float e[16];
  float local = 0.f;
  #pragma unroll
  for (int i = 0; i < 16; ++i) {
    float v = __expf(-dt[i * 256 + tid]);
    e[i] = v;
    local += v;
  }
  #pragma unroll
  for (int off = 32; off > 0; off >>= 1) local += __shfl_down(local, off);
  __shared__ float red[4];
  __shared__ float tot;
  if ((tid & 63) == 0) red[tid >> 6] = local;
  __syncthreads();
  if (tid == 0) tot = red[0] + red[1] + red[2] + red[3];
  __syncthreads();
  const float inv = 1.f / tot;
  #pragma unroll
  for (int i = 0; i < 16; ++i) w[i * 256 + tid] = e[i] * inv;
}

__device__ __forceinline__ float actf(float z, float g, float w) {
  float zc = fminf(fmaxf(z, -15.f), 15.f);
  float sz = 1.f / (1.f + __expf(-zc));
  float gc = fminf(fmaxf(g, -15.f), 15.f);
  float sg = 1.f / (1.f + __expf(-gc));
  return z * sz * w * gc * sg;
}

// ===========================================================================
// 8-phase schedule, quadrant-per-phase (full-K) variant:
// Per K-tile (4 phases), the 4 output quadrants each get one phase with the
// FULL K=64; fragments are read once and held in registers across their two
// consuming phases (reads/phase = 12,8,4,0). Each LDS half-tile is read in
// exactly ONE phase, so it frees immediately -> exactly one half-tile (2
// global_load_lds) staged per phase, every phase, with >=3-phase lead.
// vmcnt(6) at P4/P8 only (3 half-tiles in flight; FIFO retirement proven):
//   P4-wait retires through P1 -> kt+1's 4 halves (staged P6-,P7-,P8-,P1)
//   landed before P5 reads. P8-wait retires through P5 -> kt+2's halves
//   (staged P2..P5) landed before next P1. Barrier between wait and reads.
// ===========================================================================
#define BAR()    __builtin_amdgcn_s_barrier()
#define SCHED0() __builtin_amdgcn_sched_barrier(0)
#define PRIO1()  __builtin_amdgcn_s_setprio(1)
#define PRIO0()  __builtin_amdgcn_s_setprio(0)
#define WAIT_LGKM0() asm volatile("s_waitcnt lgkmcnt(0)" ::: "memory")
#define WAIT_VM6()   asm volatile("s_waitcnt vmcnt(6)" ::: "memory")

#define GLD16(gaddr, laddr) __builtin_amdgcn_global_load_lds(                 \
    (const __attribute__((address_space(1))) void*)(gaddr),                   \
    (__attribute__((address_space(3))) void*)(laddr), 16, 0, 0)

// Stage one 128-row x 64-col bf16 half-tile (16 KB): 2 chunks per thread.
// LDS dest is LINEAR (global_load_lds constraint); the XOR swizzle
// (chunk ^= row&7) is applied on the SOURCE address and undone on ds_read.
#define STAGE(ldsbase, gb, k0) do {                                           \
    GLD16((gb) + sOff  + (k0), &(ldsbase)[tid * 8]);                          \
    GLD16((gb) + sOff2 + (k0), &(ldsbase)[tid * 8 + 4096]);                   \
  } while (0)

#define TAIL() do { BAR(); WAIT_LGKM0(); SCHED0(); } while (0)

// ---------------------------------------------------------------------------
// GEMM1 fused: 256x(128 z + 128 gate) tile, BK=64, 512 threads = 8 waves.
// Wave sub-tiles realigned to staging halves: wave rows = {wmI*64..+63} u
// {128+wmI*64..+63} (a0 in Ah0, a1 in Ah1). Quadrants/phase:
//   P1: accZ[0..3] += a0 x bz   (reads a0: 8, bz: 4)
//   P2: accG[0..3] += a0 x bg   (reads bg: 4)
//   P3: accG[4..7] += a1 x bg   (reads a1: 8)
//   P4: accZ[4..7] += a1 x bz   (reads 0; bz held from P1)
// Stage slots: P1:(kt+1)Ah1, P2:(kt+2)Ah0, P3:(kt+2)Bz, P4:(kt+2)Bg,
//              P5:(kt+2)Ah1, P6:(kt+3)Ah0, P7:(kt+3)Bz, P8:(kt+3)Bg.
// LDS: A 2x32KB + Bz 2x16KB + Bg 2x16KB = 128 KiB (1 block/CU).
// ---------------------------------------------------------------------------
#define G1_NKT 32   // DM/64
#define G1_NIT 16

__global__ __launch_bounds__(512, 2) void gemm1_fused8(
    const unsigned short* __restrict__ A, const unsigned short* __restrict__ W,
    const float* __restrict__ dtw, unsigned short* __restrict__ act) {
  __shared__ unsigned short lA [2][256 * 64];
  __shared__ unsigned short lB1[2][128 * 64];
  __shared__ unsigned short lB2[2][128 * 64];

  const int tid  = threadIdx.x;
  const int lane = tid & 63;
  const int wmI  = (tid >> 6) >> 2;   // 0..1
  const int wnI  = (tid >> 6) & 3;    // 0..3 -> 32-col slice
  const int tM = blockIdx.y * 256;
  const int tN = blockIdx.x * 128;    // z col base; gate at +DI

  const int r0   = lane & 15;
  const int hi4  = lane >> 4;
  const int swz0 = (hi4 ^ (r0 & 7)) << 3;  // shorts, kk=0 chunk
  const int swz1 = swz0 ^ 32;              // kk=32 chunk
  const int aRow0 = (wmI * 64 + r0) * 64;  // a0 base (Ah0); a1 at +8192
  const int bRow  = (wnI * 32 + r0) * 64;

  // staging constants: thread -> (row, swizzled col) of a 128x64 half-tile
  const int srow = tid >> 3;
  const int scol = ((tid & 7) ^ (srow & 7)) << 3;
  const size_t sOff  = (size_t)srow * DM + scol;
  const size_t sOff2 = sOff + (size_t)64 * DM;

  const unsigned short* Ab    = A + (size_t)tM * DM;
  const unsigned short* Ab128 = Ab + (size_t)128 * DM;
  const unsigned short* B1b   = W + (size_t)tN * DM;
  const unsigned short* B2b   = W + (size_t)(tN + DI) * DM;

  f32x4 accZ[8][2], accG[8][2];
  #pragma unroll
  for (int i = 0; i < 8; ++i)
    #pragma unroll
    for (int j = 0; j < 2; ++j) {
      accZ[i][j] = f32x4{0.f, 0.f, 0.f, 0.f};
      accG[i][j] = f32x4{0.f, 0.f, 0.f, 0.f};
    }
  bf16x8 a0[4][2], a1[4][2], bz[2][2], bg[2][2];

#define G1_LDA0(b) do {                                                       \
    _Pragma("unroll") for (int i = 0; i < 4; ++i) {                           \
      a0[i][0] = *reinterpret_cast<const bf16x8*>(&lA[b][aRow0 + i*1024 + swz0]); \
      a0[i][1] = *reinterpret_cast<const bf16x8*>(&lA[b][aRow0 + i*1024 + swz1]); \
    } } while (0)
#define G1_LDA1(b) do {                                                       \
    _Pragma("unroll") for (int i = 0; i < 4; ++i) {                           \
      a1[i][0] = *reinterpret_cast<const bf16x8*>(&lA[b][8192 + aRow0 + i*1024 + swz0]); \
      a1[i][1] = *reinterpret_cast<const bf16x8*>(&lA[b][8192 + aRow0 + i*1024 + swz1]); \
    } } while (0)
#define G1_LDBZ(b) do {                                                       \
    _Pragma("unroll") for (int j = 0; j < 2; ++j) {                           \
      bz[j][0] = *reinterpret_cast<const bf16x8*>(&lB1[b][bRow + j*1024 + swz0]); \
      bz[j][1] = *reinterpret_cast<const bf16x8*>(&lB1[b][bRow + j*1024 + swz1]); \
    } } while (0)
#define G1_LDBG(b) do {                                                       \
    _Pragma("unroll") for (int j = 0; j < 2; ++j) {                           \
      bg[j][0] = *reinterpret_cast<const bf16x8*>(&lB2[b][bRow + j*1024 + swz0]); \
      bg[j][1] = *reinterpret_cast<const bf16x8*>(&lB2[b][bRow + j*1024 + swz1]); \
    } } while (0)
// 16 MFMA quadrant: kh outer so dependent acc pairs are 8 apart.
#define G1_Q(accA, ioff, af) do {                                             \
    PRIO1();                                                                  \
    _Pragma("unroll") for (int kh = 0; kh < 2; ++kh)                          \
      _Pragma("unroll") for (int i = 0; i < 4; ++i)                           \
        _Pragma("unroll") for (int j = 0; j < 2; ++j)                         \
          accA[(ioff)+i][j] = __builtin_amdgcn_mfma_f32_16x16x32_bf16(        \
              af[i][kh], G1_BF[j][kh], accA[(ioff)+i][j], 0, 0, 0);           \
    PRIO0(); SCHED0(); BAR();                                                 \
  } while (0)

  // Prologue: kt0 {Ah0,Bz,Bg,Ah1} + kt1 {Ah0,Bz,Bg} = 14 loads; vmcnt(6)
  // retires kt0's 8 -> kt0 landed; residual = kt1's 3 halves (steady shape).
  STAGE(lA[0],        Ab,    0);
  STAGE(lB1[0],       B1b,   0);
  STAGE(lB2[0],       B2b,   0);
  STAGE(&lA[0][8192], Ab128, 0);
  STAGE(lA[1],        Ab,    64);
  STAGE(lB1[1],       B1b,   64);
  STAGE(lB2[1],       B2b,   64);
  WAIT_VM6();
  BAR();

  #pragma unroll 1
  for (int t = 0; t < G1_NIT; ++t) {
    const int k1  = (2 * t + 1) * 64;
    const int kt2 = 2 * t + 2;
    const int kt3 = 2 * t + 3;
    const int k2 = (kt2 < G1_NKT ? kt2 : G1_NKT - 1) * 64;  // clamp: dummy
    const int k3 = (kt3 < G1_NKT ? kt3 : G1_NKT - 1) * 64;  // re-stage (safe)

    // ---- kt0 on buf0 ----
#define G1_BF bz
    // P1: reads a0,bz; stage (kt+1)-Ah1 -> buf1 (free since P7 of prev iter)
    G1_LDA0(0); G1_LDBZ(0);
    STAGE(&lA[1][8192], Ab128, k1);
    TAIL(); G1_Q(accZ, 0, a0);
#undef G1_BF
#define G1_BF bg
    // P2: reads bg; stage (kt+2)-Ah0 -> buf0 (Ah0 free after P1)
    G1_LDBG(0);
    STAGE(lA[0], Ab, k2);
    TAIL(); G1_Q(accG, 0, a0);
    // P3: reads a1; stage (kt+2)-Bz -> buf0 (Bz free after P1)
    G1_LDA1(0);
    STAGE(lB1[0], B1b, k2);
    TAIL(); G1_Q(accG, 4, a1);
#undef G1_BF
#define G1_BF bz
    // P4: no reads; stage (kt+2)-Bg -> buf0 (Bg free after P2); vmcnt(6)
    STAGE(lB2[0], B2b, k2);
    WAIT_VM6();
    TAIL(); G1_Q(accZ, 4, a1);
#undef G1_BF

    // ---- kt1 on buf1 ----
#define G1_BF bz
    // P5: stage (kt+2)-Ah1 -> buf0 (Ah1 free after P3)
    G1_LDA0(1); G1_LDBZ(1);
    STAGE(&lA[0][8192], Ab128, k2);
    TAIL(); G1_Q(accZ, 0, a0);
#undef G1_BF
#define G1_BF bg
    // P6: stage (kt+3)-Ah0 -> buf1 (Ah0 free after P5)
    G1_LDBG(1);
    STAGE(lA[1], Ab, k3);
    TAIL(); G1_Q(accG, 0, a0);
    // P7: stage (kt+3)-Bz -> buf1 (free after P5)
    G1_LDA1(1);
    STAGE(lB1[1], B1b, k3);
    TAIL(); G1_Q(accG, 4, a1);
#undef G1_BF
#define G1_BF bz
    // P8: stage (kt+3)-Bg -> buf1 (free after P6); vmcnt(6)
    STAGE(lB2[1], B2b, k3);
    WAIT_VM6();
    TAIL(); G1_Q(accZ, 4, a1);
#undef G1_BF
  }

  // Register epilogue. C/D layout: col = lane&15, row = (lane>>4)*4 + reg.
  // Row map: i<4 -> wmI*64 + i*16 (m0/Ah0); i>=4 -> 128 + wmI*64 + (i-4)*16.
  const int qr   = hi4 << 2;
  const int colb = tN + wnI * 32 + r0;
  const float w0 = dtw[colb];
  const float w1 = dtw[colb + 16];
  #pragma unroll
  for (int i = 0; i < 8; ++i) {
    const int rowb = tM + wmI * 64 + ((i & 3) << 4) + ((i >> 2) << 7) + qr;
    #pragma unroll
    for (int r = 0; r < 4; ++r) {
      const size_t base = (size_t)(rowb + r) * DI + colb;
      act[base]      = f2bf(actf(accZ[i][0][r], accG[i][0][r], w0));
      act[base + 16] = f2bf(actf(accZ[i][1][r], accG[i][1][r], w1));
    }
  }
#undef G1_LDA0
#undef G1_LDA1
#undef G1_LDBZ
#undef G1_LDBG
#undef G1_Q
}

// ---------------------------------------------------------------------------
// GEMM2: 256x256 8-phase NT bf16 GEMM with fused residual (fp32 out).
// out[t,d] = sum_e act[t,e]*W_out[d,e] + x[t,d].  K = DI = 4096.
// Same quadrant-per-phase schedule; col halves: b0 in Bh0 (rows 0-127 =
// cols wnI*32..), b1 in Bh1 (rows 128-255 = cols 128+wnI*32..).
//   P1: acc[0..3][0..1] += a0 x b0   (reads a0: 8, b0: 4)
//   P2: acc[0..3][2..3] += a0 x b1   (reads b1: 4)
//   P3: acc[4..7][2..3] += a1 x b1   (reads a1: 8)
//   P4: acc[4..7][0..1] += a1 x b0   (reads 0; b0 held from P1)
// ---------------------------------------------------------------------------
#define G2_NKT 64   // DI/64
#define G2_NIT 32

__global__ __launch_bounds__(512, 2) void gemm2_res8(
    const unsigned short* __restrict__ A, const unsigned short* __restrict__ Bm,
    float* __restrict__ out, const float* __restrict__ ident) {
  __shared__ unsigned short lA[2][256 * 64];
  __shared__ unsigned short lB[2][256 * 64];

  const int tid  = threadIdx.x;
  const int lane = tid & 63;
  const int wmI  = (tid >> 6) >> 2;   // 0..1
  const int wnI  = (tid >> 6) & 3;    // 0..3 -> 32-col slice (x2 halves)
  const int tM = blockIdx.y * 256;
  const int tN = blockIdx.x * 256;

  const int r0   = lane & 15;
  const int hi4  = lane >> 4;
  const int swz0 = (hi4 ^ (r0 & 7)) << 3;
  const int swz1 = swz0 ^ 32;
  const int aRow0 = (wmI * 64 + r0) * 64;
  const int bRow  = (wnI * 32 + r0) * 64;

  const int srow = tid >> 3;
  const int scol = ((tid & 7) ^ (srow & 7)) << 3;
  const size_t sOff  = (size_t)srow * DI + scol;
  const size_t sOff2 = sOff + (size_t)64 * DI;

  const unsigned short* Ab    = A + (size_t)tM * DI;
  const unsigned short* Ab128 = Ab + (size_t)128 * DI;
  const unsigned short* Bb    = Bm + (size_t)tN * DI;
  const unsigned short* Bb128 = Bb + (size_t)128 * DI;

  f32x4 acc[8][4];
  #pragma unroll
  for (int i = 0; i < 8; ++i)
    #pragma unroll
    for (int j = 0; j < 4; ++j) acc[i][j] = f32x4{0.f, 0.f, 0.f, 0.f};
  bf16x8 a0[4][2], a1[4][2], b0[2][2], b1[2][2];

#define G2_LDA0(b) do {                                                       \
    _Pragma("unroll") for (int i = 0; i < 4; ++i) {                           \
      a0[i][0] = *reinterpret_cast<const bf16x8*>(&lA[b][aRow0 + i*1024 + swz0]); \
      a0[i][1] = *reinterpret_cast<const bf16x8*>(&lA[b][aRow0 + i*1024 + swz1]); \
    } } while (0)
#define G2_LDA1(b) do {                                                       \
    _Pragma("unroll") for (int i = 0; i < 4; ++i) {                           \
      a1[i][0] = *reinterpret_cast<const bf16x8*>(&lA[b][8192 + aRow0 + i*1024 + swz0]); \
      a1[i][1] = *reinterpret_cast<const bf16x8*>(&lA[b][8192 + aRow0 + i*1024 + swz1]); \
    } } while (0)
#define G2_LDB0(b) do {                                                       \
    _Pragma("unroll") for (int j = 0; j < 2; ++j) {                           \
      b0[j][0] = *reinterpret_cast<const bf16x8*>(&lB[b][bRow + j*1024 + swz0]); \
      b0[j][1] = *reinterpret_cast<const bf16x8*>(&lB[b][bRow + j*1024 + swz1]); \
    } } while (0)
#define G2_LDB1(b) do {                                                       \
    _Pragma("unroll") for (int j = 0; j < 2; ++j) {                           \
      b1[j][0] = *reinterpret_cast<const bf16x8*>(&lB[b][8192 + bRow + j*1024 + swz0]); \
      b1[j][1] = *reinterpret_cast<const bf16x8*>(&lB[b][8192 + bRow + j*1024 + swz1]); \
    } } while (0)
#define G2_Q(ioff, joff, af, bf) do {                                         \
    PRIO1();                                                                  \
    _Pragma("unroll") for (int kh = 0; kh < 2; ++kh)                          \
      _Pragma("unroll") for (int i = 0; i < 4; ++i)                           \
        _Pragma("unroll") for (int j = 0; j < 2; ++j)                         \
          acc[(ioff)+i][(joff)+j] = __builtin_amdgcn_mfma_f32_16x16x32_bf16(  \
              af[i][kh], bf[j][kh], acc[(ioff)+i][(joff)+j], 0, 0, 0);        \
    PRIO0(); SCHED0(); BAR();                                                 \
  } while (0)

  // Prologue: kt0 {Ah0,Bh0,Bh1,Ah1} + kt1 {Ah0,Bh0,Bh1}; vmcnt(6).
  STAGE(lA[0],        Ab,    0);
  STAGE(lB[0],        Bb,    0);
  STAGE(&lB[0][8192], Bb128, 0);
  STAGE(&lA[0][8192], Ab128, 0);
  STAGE(lA[1],        Ab,    64);
  STAGE(lB[1],        Bb,    64);
  STAGE(&lB[1][8192], Bb128, 64);
  WAIT_VM6();
  BAR();

  #pragma unroll 1
  for (int t = 0; t < G2_NIT; ++t) {
    const int k1  = (2 * t + 1) * 64;
    const int kt2 = 2 * t + 2;
    const int kt3 = 2 * t + 3;
    const int k2 = (kt2 < G2_NKT ? kt2 : G2_NKT - 1) * 64;
    const int k3 = (kt3 < G2_NKT ? kt3 : G2_NKT - 1) * 64;

    // ---- kt0 on buf0 ----
    // P1: stage (kt+1)-Ah1 -> buf1
    G2_LDA0(0); G2_LDB0(0);
    STAGE(&lA[1][8192], Ab128, k1);
    TAIL(); G2_Q(0, 0, a0, b0);
    // P2: stage (kt+2)-Ah0 -> buf0
    G2_LDB1(0);
    STAGE(lA[0], Ab, k2);
    TAIL(); G2_Q(0, 2, a0, b1);
    // P3: stage (kt+2)-Bh0 -> buf0
    G2_LDA1(0);
    STAGE(lB[0], Bb, k2);
    TAIL(); G2_Q(4, 2, a1, b1);
    // P4: stage (kt+2)-Bh1 -> buf0; vmcnt(6)
    STAGE(&lB[0][8192], Bb128, k2);
    WAIT_VM6();
    TAIL(); G2_Q(4, 0, a1, b0);

    // ---- kt1 on buf1 ----
    // P5: stage (kt+2)-Ah1 -> buf0
    G2_LDA0(1); G2_LDB0(1);
    STAGE(&lA[0][8192], Ab128, k2);
    TAIL(); G2_Q(0, 0, a0, b0);
    // P6: stage (kt+3)-Ah0 -> buf1
    G2_LDB1(1);
    STAGE(lA[1], Ab, k3);
    TAIL(); G2_Q(0, 2, a0, b1);
    // P7: stage (kt+3)-Bh0 -> buf1
    G2_LDA1(1);
    STAGE(lB[1], Bb, k3);
    TAIL(); G2_Q(4, 2, a1, b1);
    // P8: stage (kt+3)-Bh1 -> buf1; vmcnt(6)
    STAGE(&lB[1][8192], Bb128, k3);
    WAIT_VM6();
    TAIL(); G2_Q(4, 0, a1, b0);
  }

  // Epilogue: row i<4 -> wmI*64+i*16, i>=4 -> 128+wmI*64+(i-4)*16;
  //           col j<2 -> wnI*32+j*16, j>=2 -> 128+wnI*32+(j-2)*16.
  const int qr   = hi4 << 2;
  const int colb = tN + wnI * 32 + r0;
  #pragma unroll
  for (int i = 0; i < 8; ++i) {
    const int rowb = tM + wmI * 64 + ((i & 3) << 4) + ((i >> 2) << 7) + qr;
    #pragma unroll
    for (int r = 0; r < 4; ++r) {
      const size_t rowoff = (size_t)(rowb + r) * DM;
      #pragma unroll
      for (int j = 0; j < 4; ++j) {
        const size_t idx = rowoff + colb + ((j & 1) << 4) + ((j >> 1) << 7);
        out[idx] = acc[i][j][r] + ident[idx];
      }
    }
  }
#undef G2_LDA0
#undef G2_LDA1
#undef G2_LDB0
#undef G2_LDB1
#undef G2_Q
}

// ---------------------------------------------------------------------------
// Workspace layout (~160 MB):
//   [0, 32MB)     xn bf16 [8192][2048]
//   [32, 64MB)    W_in bf16 [8192][2048]
//   [64, 80MB)    W_out bf16 [2048][4096]
//   [80MB, +16K)  dt_weights fp32 [4096]
//   [96, 160MB)   act bf16 [8192][4096]
// ---------------------------------------------------------------------------
extern "C" void kernel_launch(void* const* d_in, const int* in_sizes, int n_in,
                              void* d_out, int out_size, void* d_ws, size_t ws_size,
                              hipStream_t stream) {
  const float* x     = (const float*)d_in[0];
  const float* gamma = (const float*)d_in[1];
  const float* beta  = (const float*)d_in[2];
  const float* W_in  = (const float*)d_in[3];
  const float* W_out = (const float*)d_in[4];
  const float* dt    = (const float*)d_in[5];
  float* out = (float*)d_out;

  char* ws = (char*)d_ws;
  unsigned short* xn     = (unsigned short*)(ws);
  unsigned short* win_b  = (unsigned short*)(ws + ((size_t)32 << 20));
  unsigned short* wout_b = (unsigned short*)(ws + ((size_t)64 << 20));
  float*          dtw    = (float*)(ws + ((size_t)80 << 20));
  unsigned short* act    = (unsigned short*)(ws + ((size_t)96 << 20));

  const int n4_in  = TWO_DI * DM / 4;
  const int n4_out = DM * DI / 4;

  ln_kernel<<<T_TOK, 256, 0, stream>>>(x, gamma, beta, xn);
  cvt_both<<<(n4_in + n4_out + 255) / 256, 256, 0, stream>>>(
      W_in, win_b, n4_in, W_out, wout_b, n4_out);
  dt_softmax<<<1, 256, 0, stream>>>(dt, dtw);

  // GEMM1 + gated activation fused, 8-phase quadrant schedule
  gemm1_fused8<<<dim3(DI / 128, T_TOK / 256), 512, 0, stream>>>(
      xn, win_b, dtw, act);

  // GEMM2 8-phase quadrant schedule: out = act.W_out^T + x
  gemm2_res8<<<dim3(DM / 256, T_TOK / 256), 512, 0, stream>>>(
      act, wout_b, out, x);
}